// Round 4
// baseline (193.082 us; speedup 1.0000x reference)
//
#include <hip/hip_runtime.h>
#include <cstdint>
#include <cstddef>

// Problem constants (from reference)
constexpr int N  = 2048;     // parents
constexpr int C  = 256;      // in channels
constexpr int CO = 128;      // out channels
constexpr int M  = 16384;    // children (8*N)
constexpr int G  = 66;       // padded child grid dim (S2+2)
constexpr int KP2 = 4;       // k-split parts for conv2 (same as round-2)
constexpr int KCHUNK2 = 7;   // neighbors per part (7,7,7,6)
constexpr int UW = 27 * CO;  // U row width = 3456
constexpr float EPS = 1e-6f;

using bf8 = __attribute__((ext_vector_type(8))) short;   // 8 bf16 (4 VGPRs)
using f4  = __attribute__((ext_vector_type(4))) float;   // 4 f32 acc

static __device__ __forceinline__ unsigned short f2bf(float f) {
  unsigned u = __float_as_uint(f);
  u += 0x7fffu + ((u >> 16) & 1u);     // round-to-nearest-even
  return (unsigned short)(u >> 16);
}
static __device__ __forceinline__ float bf2f(unsigned short s) {
  return __uint_as_float((unsigned)s << 16);
}

// ---------------- prep: grid sentinel + zero rows + both weight transposes ---
// (round-2 style; adds nidxtc sentinel prefill + nact=0)
__global__ void k_prep(int* __restrict__ grid, unsigned short* __restrict__ h,
                       unsigned short* __restrict__ h1,
                       const float* __restrict__ c1w, unsigned short* __restrict__ w1t,
                       const float* __restrict__ c2w, unsigned short* __restrict__ w2t,
                       int* __restrict__ nidxtc, int* __restrict__ nact) {
  int i = blockIdx.x * 256 + threadIdx.x;
  if (i < G * G * G) grid[i] = M;
  if (i < 27 * M) nidxtc[i] = M;       // sentinel: h1 zero row
  if (i < C)  h[(size_t)N * C + i] = 0;
  if (i < CO) h1[(size_t)M * CO + i] = 0;
  if (i == 0) *nact = 0;
  if (i < 27 * C * CO) {       // w1t[k][o][c] = c1w[k][c][o]
    int c = i % C;
    int rest = i / C;
    int o = rest % CO;
    int k = rest / CO;
    w1t[i] = f2bf(c1w[((size_t)(k * C + c)) * CO + o]);
  }
  if (i < 27 * CO * CO) {      // w2t[k][o][c] = c2w[k][c][o]
    int c = i % CO;
    int rest = i / CO;
    int o = rest % CO;
    int k = rest / CO;
    w2t[i] = f2bf(c2w[((size_t)(k * CO + c)) * CO + o]);
  }
}

// ------- per-parent: subdiv + mask + LN + silu -> h (bf16); + child scatter --
// Also assigns compacted active-row slots: inv[m] = slot or -1.
__global__ __launch_bounds__(256) void k_rownorm(
    const float* __restrict__ feats, const float* __restrict__ n1w,
    const float* __restrict__ n1b, const float* __restrict__ sdw,
    const float* __restrict__ sdb, float* __restrict__ out_subdiv,
    unsigned short* __restrict__ h, int* __restrict__ pidx,
    int* __restrict__ inv, int* __restrict__ nact,
    const int* __restrict__ coords, int* __restrict__ grid) {
  int n = blockIdx.x, t = threadIdx.x;
  float x = feats[(size_t)n * C + t];
  float4 w0 = *(const float4*)(sdw + t * 8);
  float4 w1 = *(const float4*)(sdw + t * 8 + 4);
  float v[10] = {x * w0.x, x * w0.y, x * w0.z, x * w0.w,
                 x * w1.x, x * w1.y, x * w1.z, x * w1.w, x, x * x};
#pragma unroll
  for (int mk = 1; mk < 64; mk <<= 1) {
#pragma unroll
    for (int j = 0; j < 10; ++j) v[j] += __shfl_xor(v[j], mk, 64);
  }
  __shared__ float red[4][10];
  int wave = t >> 6, lane = t & 63;
  if (lane == 0) {
#pragma unroll
    for (int j = 0; j < 10; ++j) red[wave][j] = v[j];
  }
  __syncthreads();
  float sums[10];
#pragma unroll
  for (int j = 0; j < 10; ++j)
    sums[j] = red[0][j] + red[1][j] + red[2][j] + red[3][j];
  float mean = sums[8] / (float)C;
  float var  = sums[9] / (float)C - mean * mean;
  float rstd = rsqrtf(var + EPS);
  if (t < 8) {
    float sd = sums[t] + sdb[t];
    out_subdiv[(size_t)n * 8 + t] = sd;
    bool mk = sd > 0.f;
    int m = n * 8 + t;
    pidx[m] = mk ? n : N;              // h/U row index (N = zero/skip)
    inv[m] = mk ? atomicAdd(nact, 1) : -1;
    // scatter child id into lookup grid (grid pre-inited to M by k_prep)
    int xx = coords[n * 3 + 0] * 2 + ((t >> 2) & 1) + 1;
    int yy = coords[n * 3 + 1] * 2 + ((t >> 1) & 1) + 1;
    int zz = coords[n * 3 + 2] * 2 + (t & 1) + 1;
    grid[(xx * G + yy) * G + zz] = m;
  }
  float y  = (x - mean) * rstd * n1w[t] + n1b[t];
  float sl = y / (1.f + __expf(-y));
  h[(size_t)n * C + t] = f2bf(sl);
}

// ---- build tables: g1t[k][m] (full, for conv1 combine) and nidxtc[k][ci]
// (compacted, for conv2 gather; sentinel-prefilled by k_prep) ----------------
__global__ void k_nidx(const int* __restrict__ coords, const int* __restrict__ grid,
                       const int* __restrict__ pidx, const int* __restrict__ inv,
                       int* __restrict__ g1t, int* __restrict__ nidxtc) {
  int idx = blockIdx.x * 256 + threadIdx.x;
  if (idx >= M * 27) return;
  int m = idx & (M - 1);          // M = 2^14
  int k = idx >> 14;
  int p = m >> 3, j = m & 7;
  int dx = k / 9 - 1;
  int dy = (k / 3) % 3 - 1;
  int dz = k % 3 - 1;
  int x = coords[p * 3 + 0] * 2 + ((j >> 2) & 1) + 1 + dx;
  int y = coords[p * 3 + 1] * 2 + ((j >> 1) & 1) + 1 + dy;
  int z = coords[p * 3 + 2] * 2 + (j & 1) + 1 + dz;
  int gv = grid[(x * G + y) * G + z];
  g1t[idx] = (gv == M) ? N : pidx[gv];  // index into U (N = skip/zero)
  int ci = inv[m];
  if (ci >= 0) nidxtc[(size_t)k * M + ci] = gv;   // index into h1
}

// ---------------- skip GEMM: s = feats @ skip_w + skip_b  (f32) --------------
__global__ __launch_bounds__(256) void k_skip(const float* __restrict__ feats,
                                              const float* __restrict__ skw,
                                              const float* __restrict__ skb,
                                              float* __restrict__ s) {
  __shared__ float tile[32][36];
  int t = threadIdx.x;
  int rb = (blockIdx.x >> 1) * 32;        // 32 rows per block
  int ob = (blockIdx.x & 1) * 64;         // 64-col half
  int o = ob + (t & 63);
  int rg = (t >> 6) * 8;                  // 8 rows per wave-group
  float acc[8] = {0, 0, 0, 0, 0, 0, 0, 0};
  for (int cb = 0; cb < C; cb += 32) {
    __syncthreads();
    int row = t >> 3, cc = (t & 7) * 4;
    *(float4*)&tile[row][cc] =
        *(const float4*)(feats + (size_t)(rb + row) * C + cb + cc);
    __syncthreads();
    for (int c = 0; c < 32; ++c) {
      float wv = skw[(size_t)(cb + c) * CO + o];
#pragma unroll
      for (int r = 0; r < 8; ++r) acc[r] += tile[rg + r][c] * wv;
    }
  }
  float bv = skb[o];
#pragma unroll
  for (int r = 0; r < 8; ++r) s[(size_t)(rb + rg + r) * CO + o] = acc[r] + bv;
}

// ---------------- dense GEMM: U[n][k*128+o] = h[n][:] . w1t[k][o][:]  --------
template <int CIN, int NCB>
__global__ __launch_bounds__(256, 3) void k_dgemm(
    const unsigned short* __restrict__ src, const unsigned short* __restrict__ wt,
    float* __restrict__ U) {
  __shared__ unsigned short sA[2][128 * 32];
  __shared__ unsigned short sB[2][128 * 32];
  const int t = threadIdx.x;
  const int w = t >> 6, lane = t & 63;
  const int quad = lane >> 4, ln = lane & 15;
  const int m0 = blockIdx.x * 128;
  const int k = blockIdx.y;                  // tap index = 128-col block of U
  const int rh = (w >> 1) * 64, ch = (w & 1) * 64;

  const int row2 = t >> 1;
  const int c0 = (t & 1) * 2;
  const int x3 = (row2 >> 1) & 3;
  const int wsl0 = row2 * 32 + ((c0) ^ x3) * 8;
  const int wsl1 = row2 * 32 + ((c0 + 1) ^ x3) * 8;

  const unsigned short* pa_base = src + (size_t)(m0 + row2) * CIN + c0 * 8;
  const unsigned short* pb_base =
      wt + ((size_t)k * CO + row2) * CIN + c0 * 8;

  bf8 ra0, ra1, rb0, rb1;
  auto loadreg = [&](int s) {
    const unsigned short* pa = pa_base + s * 32;
    const unsigned short* pb = pb_base + s * 32;
    ra0 = *(const bf8*)(pa);
    ra1 = *(const bf8*)(pa + 8);
    rb0 = *(const bf8*)(pb);
    rb1 = *(const bf8*)(pb + 8);
  };
  auto writelds = [&](int buf) {
    *(bf8*)(sA[buf] + wsl0) = ra0;
    *(bf8*)(sA[buf] + wsl1) = ra1;
    *(bf8*)(sB[buf] + wsl0) = rb0;
    *(bf8*)(sB[buf] + wsl1) = rb1;
  };

  f4 acc[16];
  f4 zero = {0.f, 0.f, 0.f, 0.f};
#pragma unroll
  for (int i = 0; i < 16; ++i) acc[i] = zero;

  const int slot = (quad ^ ((ln >> 1) & 3)) * 8;

  loadreg(0);
  writelds(0);
  for (int s = 0; s < NCB; ++s) {
    const bool have = (s + 1 < NCB);
    if (have) loadreg(s + 1);
    __syncthreads();
    const unsigned short* pa = sA[s & 1];
    const unsigned short* pb = sB[s & 1];
    bf8 av[4], bv[4];
#pragma unroll
    for (int ti = 0; ti < 4; ++ti)
      av[ti] = *(const bf8*)(pa + (rh + ti * 16 + ln) * 32 + slot);
#pragma unroll
    for (int tj = 0; tj < 4; ++tj)
      bv[tj] = *(const bf8*)(pb + (ch + tj * 16 + ln) * 32 + slot);
#pragma unroll
    for (int ti = 0; ti < 4; ++ti)
#pragma unroll
      for (int tj = 0; tj < 4; ++tj)
        acc[ti * 4 + tj] = __builtin_amdgcn_mfma_f32_16x16x32_bf16(
            av[ti], bv[tj], acc[ti * 4 + tj], 0, 0, 0);
    if (have) writelds((s + 1) & 1);
  }

  // store f32: D layout col=ln, row=quad*4+rr; U row stride UW=3456
#pragma unroll
  for (int ti = 0; ti < 4; ++ti) {
    int mrow = rh + ti * 16 + quad * 4;
#pragma unroll
    for (int tj = 0; tj < 4; ++tj) {
      int co = ch + tj * 16 + ln;
#pragma unroll
      for (int rr = 0; rr < 4; ++rr)
        U[(size_t)(m0 + mrow + rr) * UW + k * CO + co] = acc[ti * 4 + tj][rr];
    }
  }
}

// --- conv1 combine: out1[m] = sum_k U[g1t[k][m]][k*128+:] + b1; LN; silu -> h1
__global__ __launch_bounds__(256) void k_g1sum(
    const float* __restrict__ U, const int* __restrict__ g1t,
    const float* __restrict__ b1, unsigned short* __restrict__ h1) {
  int wave = threadIdx.x >> 6, lane = threadIdx.x & 63;
  int m = blockIdx.x * 4 + wave;
  float a0 = b1[2 * lane], a1 = b1[2 * lane + 1];
#pragma unroll
  for (int k = 0; k < 27; ++k) {
    int g = g1t[k * M + m];          // wave-uniform
    if (g < N) {
      float2 v = *(const float2*)(U + (size_t)g * UW + k * CO + 2 * lane);
      a0 += v.x; a1 += v.y;
    }
  }
  float sum = a0 + a1, sq = a0 * a0 + a1 * a1;
#pragma unroll
  for (int mk = 1; mk < 64; mk <<= 1) {
    sum += __shfl_xor(sum, mk, 64);
    sq  += __shfl_xor(sq, mk, 64);
  }
  float mean = sum / (float)CO;
  float var  = sq / (float)CO - mean * mean;
  float rstd = rsqrtf(var + EPS);
  float y0 = (a0 - mean) * rstd;
  float y1 = (a1 - mean) * rstd;
  float s0 = y0 / (1.f + __expf(-y0));
  float s1 = y1 / (1.f + __expf(-y1));
  *(ushort2*)(h1 + (size_t)m * CO + 2 * lane) = ushort2{f2bf(s0), f2bf(s1)};
}

// -------- implicit-GEMM conv2 over COMPACTED active rows; early-exit --------
template <int CIN, int NCB, int KCH>
__global__ __launch_bounds__(256, 3) void k_conv(
    const unsigned short* __restrict__ src, const int* __restrict__ gt,
    const unsigned short* __restrict__ wt, unsigned short* __restrict__ part,
    const int* __restrict__ nact) {
  const int m0 = blockIdx.x * 128;
  if (m0 >= *nact) return;             // whole block inactive
  __shared__ unsigned short sA[2][128 * 32];   // 8 KB per buf
  __shared__ unsigned short sB[2][128 * 32];
  const int t = threadIdx.x;
  const int w = t >> 6, lane = t & 63;
  const int quad = lane >> 4, ln = lane & 15;
  const int kpart = blockIdx.y;
  const int k0 = kpart * KCH;
  const int nk = min(KCH, 27 - k0);
  const int nstage = nk * NCB;
  const int rh = (w >> 1) * 64, ch = (w & 1) * 64;

  const int row2 = t >> 1;
  const int c0 = (t & 1) * 2;
  const int x3 = (row2 >> 1) & 3;
  const int wsl0 = row2 * 32 + ((c0) ^ x3) * 8;
  const int wsl1 = row2 * 32 + ((c0 + 1) ^ x3) * 8;

  int ga[KCH];
#pragma unroll
  for (int kk = 0; kk < KCH; ++kk)
    ga[kk] = (kk < nk) ? gt[(size_t)(k0 + kk) * M + m0 + row2] : 0;

  bf8 ra0, ra1, rb0, rb1;
  auto loadreg = [&](int s) {
    const int kk = s / NCB;
    const int cb = s - kk * NCB;
    const unsigned short* pa = src + (size_t)ga[kk] * CIN + cb * 32 + c0 * 8;
    const unsigned short* pb =
        wt + ((size_t)(k0 + kk) * CO + row2) * CIN + cb * 32 + c0 * 8;
    ra0 = *(const bf8*)(pa);
    ra1 = *(const bf8*)(pa + 8);
    rb0 = *(const bf8*)(pb);
    rb1 = *(const bf8*)(pb + 8);
  };
  auto writelds = [&](int buf) {
    *(bf8*)(sA[buf] + wsl0) = ra0;
    *(bf8*)(sA[buf] + wsl1) = ra1;
    *(bf8*)(sB[buf] + wsl0) = rb0;
    *(bf8*)(sB[buf] + wsl1) = rb1;
  };

  f4 acc[16];
  f4 zero = {0.f, 0.f, 0.f, 0.f};
#pragma unroll
  for (int i = 0; i < 16; ++i) acc[i] = zero;

  const int slot = (quad ^ ((ln >> 1) & 3)) * 8;

  loadreg(0);
  writelds(0);
  for (int s = 0; s < nstage; ++s) {
    const bool have = (s + 1 < nstage);
    if (have) loadreg(s + 1);
    __syncthreads();
    const unsigned short* pa = sA[s & 1];
    const unsigned short* pb = sB[s & 1];
    bf8 av[4], bv[4];
#pragma unroll
    for (int ti = 0; ti < 4; ++ti)
      av[ti] = *(const bf8*)(pa + (rh + ti * 16 + ln) * 32 + slot);
#pragma unroll
    for (int tj = 0; tj < 4; ++tj)
      bv[tj] = *(const bf8*)(pb + (ch + tj * 16 + ln) * 32 + slot);
#pragma unroll
    for (int ti = 0; ti < 4; ++ti)
#pragma unroll
      for (int tj = 0; tj < 4; ++tj)
        acc[ti * 4 + tj] = __builtin_amdgcn_mfma_f32_16x16x32_bf16(
            av[ti], bv[tj], acc[ti * 4 + tj], 0, 0, 0);
    if (have) writelds((s + 1) & 1);
  }

  unsigned short* pp = part + ((size_t)kpart * M + m0) * CO;
#pragma unroll
  for (int ti = 0; ti < 4; ++ti) {
    int mrow = rh + ti * 16 + quad * 4;
#pragma unroll
    for (int tj = 0; tj < 4; ++tj) {
      int co = ch + tj * 16 + ln;
#pragma unroll
      for (int rr = 0; rr < 4; ++rr)
        pp[(size_t)(mrow + rr) * CO + co] = f2bf(acc[ti * 4 + tj][rr]);
    }
  }
}

// -- reduce 2: inactive m -> zeros; active -> sum KP2 partials[ci]+bias+skip --
__global__ __launch_bounds__(256) void k_r2(const unsigned short* __restrict__ p,
                                            const float* __restrict__ bias,
                                            const float* __restrict__ sres,
                                            const int* __restrict__ inv,
                                            float* __restrict__ out) {
  int i = blockIdx.x * 256 + threadIdx.x;   // i in [0, M*CO/4)
  int m = i >> 5;                            // 32 groups of 4 per row
  int o4 = (i & 31) * 4;
  int ci = inv[m];
  float4 r = {0.f, 0.f, 0.f, 0.f};
  if (ci >= 0) {
    float4 acc = *(const float4*)(bias + o4);
#pragma unroll
    for (int q = 0; q < KP2; ++q) {
      ushort4 a = *(const ushort4*)(p + ((size_t)q * M + ci) * CO + o4);
      acc.x += bf2f(a.x); acc.y += bf2f(a.y);
      acc.z += bf2f(a.z); acc.w += bf2f(a.w);
    }
    float4 s = *(const float4*)(sres + (size_t)(m >> 3) * CO + o4);
    r.x = acc.x + s.x;
    r.y = acc.y + s.y;
    r.z = acc.z + s.z;
    r.w = acc.w + s.w;
  }
  *(float4*)(out + (size_t)m * CO + o4) = r;
}

// ---------------- launcher ----------------------------------------------------
extern "C" void kernel_launch(void* const* d_in, const int* in_sizes, int n_in,
                              void* d_out, int out_size, void* d_ws, size_t ws_size,
                              hipStream_t stream) {
  const float* feats = (const float*)d_in[0];
  const float* n1w   = (const float*)d_in[1];
  const float* n1b   = (const float*)d_in[2];
  const float* sdw   = (const float*)d_in[3];
  const float* sdb   = (const float*)d_in[4];
  const float* c1w   = (const float*)d_in[5];
  const float* c1b   = (const float*)d_in[6];
  const float* c2w   = (const float*)d_in[7];
  const float* c2b   = (const float*)d_in[8];
  const float* skw   = (const float*)d_in[9];
  const float* skb   = (const float*)d_in[10];
  const int* coords  = (const int*)d_in[11];
  float* out = (float*)d_out;   // [M*CO] conv output, then [N*8] subdiv

  char* ws = (char*)d_ws;
  size_t off = 0;
  auto alloc = [&](size_t bytes) -> char* {
    char* p = ws + off;
    off += (bytes + 255) & ~(size_t)255;
    return p;
  };
  unsigned short* h    = (unsigned short*)alloc((size_t)(N + 1) * C * 2);
  unsigned short* h1   = (unsigned short*)alloc((size_t)(M + 1) * CO * 2);
  int*   grid   = (int*)alloc((size_t)G * G * G * 4);
  int*   nidxtc = (int*)alloc((size_t)27 * M * 4);
  int*   g1t    = (int*)alloc((size_t)27 * M * 4);
  int*   pidx   = (int*)alloc((size_t)M * 4);
  int*   inv    = (int*)alloc((size_t)M * 4);
  int*   nact   = (int*)alloc(256);
  float* sres   = (float*)alloc((size_t)N * CO * 4);
  unsigned short* w1t = (unsigned short*)alloc((size_t)27 * CO * C * 2);
  unsigned short* w2t = (unsigned short*)alloc((size_t)27 * CO * CO * 2);
  float* U = (float*)alloc((size_t)N * UW * 4);                 // 28.3 MB
  unsigned short* pc  = (unsigned short*)alloc((size_t)KP2 * M * CO * 2);

  k_prep<<<(27 * C * CO + 255) / 256, 256, 0, stream>>>(grid, h, h1, c1w, w1t,
                                                        c2w, w2t, nidxtc, nact);
  k_rownorm<<<N, 256, 0, stream>>>(feats, n1w, n1b, sdw, sdb,
                                   out + (size_t)M * CO, h, pidx, inv, nact,
                                   coords, grid);
  k_nidx<<<(M * 27 + 255) / 256, 256, 0, stream>>>(coords, grid, pidx, inv,
                                                   g1t, nidxtc);
  k_skip<<<128, 256, 0, stream>>>(feats, skw, skb, sres);

  // conv1 via factorization: dense U-GEMM (2048 x 3456 x 256) ...
  k_dgemm<C, 8><<<dim3(N / 128, 27), 256, 0, stream>>>(h, w1t, U);
  // ... then gather-add over 27 taps, fused bias + LN + silu -> h1
  k_g1sum<<<M / 4, 256, 0, stream>>>(U, g1t, c1b, h1);

  // conv2: implicit GEMM over compacted active rows (~M/2), k-split 4x7
  // (grid shape identical to round-2; ~half the blocks early-exit)
  k_conv<CO, 4, KCHUNK2><<<dim3(M / 128, KP2), 256, 0, stream>>>(h1, nidxtc,
                                                                 w2t, pc, nact);
  k_r2<<<M * CO / 4 / 256, 256, 0, stream>>>(pc, c2b, sres, inv, out);
}

// Round 5
// 182.884 us; speedup vs baseline: 1.0558x; 1.0558x over previous
//
#include <hip/hip_runtime.h>
#include <cstdint>
#include <cstddef>

// Problem constants (from reference)
constexpr int N  = 2048;     // parents
constexpr int C  = 256;      // in channels
constexpr int CO = 128;      // out channels
constexpr int M  = 16384;    // children (8*N)
constexpr int G  = 66;       // padded child grid dim (S2+2)
constexpr int KP2 = 4;       // k-split parts for conv2
constexpr int KCHUNK2 = 7;   // neighbors per part (7,7,7,6)
constexpr int UW = 27 * CO;  // U row width = 3456
constexpr float EPS = 1e-6f;

// fused-middle-kernel block roles
constexpr int DG_BLK = (N / 128) * 27;   // 432 dense-GEMM blocks (first = long pole)
constexpr int NI_BLK = 27 * M / 256;     // 1728 nidx blocks
constexpr int SK_BLK = 128;              // 128 skip blocks

using bf8 = __attribute__((ext_vector_type(8))) short;   // 8 bf16 (4 VGPRs)
using f4  = __attribute__((ext_vector_type(4))) float;   // 4 f32 acc

static __device__ __forceinline__ unsigned short f2bf(float f) {
  unsigned u = __float_as_uint(f);
  u += 0x7fffu + ((u >> 16) & 1u);     // round-to-nearest-even
  return (unsigned short)(u >> 16);
}
static __device__ __forceinline__ float bf2f(unsigned short s) {
  return __uint_as_float((unsigned)s << 16);
}

// ---------------- prep: grid sentinel + zero rows + both weight transposes ---
__global__ void k_prep(int* __restrict__ grid, unsigned short* __restrict__ h,
                       unsigned short* __restrict__ h1,
                       const float* __restrict__ c1w, unsigned short* __restrict__ w1t,
                       const float* __restrict__ c2w, unsigned short* __restrict__ w2t) {
  int i = blockIdx.x * 256 + threadIdx.x;
  if (i < G * G * G) grid[i] = M;
  if (i < C)  h[(size_t)N * C + i] = 0;
  if (i < CO) h1[(size_t)M * CO + i] = 0;
  if (i < 27 * C * CO) {       // w1t[k][o][c] = c1w[k][c][o]
    int c = i % C;
    int rest = i / C;
    int o = rest % CO;
    int k = rest / CO;
    w1t[i] = f2bf(c1w[((size_t)(k * C + c)) * CO + o]);
  }
  if (i < 27 * CO * CO) {      // w2t[k][o][c] = c2w[k][c][o]
    int c = i % CO;
    int rest = i / CO;
    int o = rest % CO;
    int k = rest / CO;
    w2t[i] = f2bf(c2w[((size_t)(k * CO + c)) * CO + o]);
  }
}

// ------- per-parent: subdiv + mask + LN + silu -> h (bf16); + child scatter --
__global__ __launch_bounds__(256) void k_rownorm(
    const float* __restrict__ feats, const float* __restrict__ n1w,
    const float* __restrict__ n1b, const float* __restrict__ sdw,
    const float* __restrict__ sdb, float* __restrict__ out_subdiv,
    unsigned short* __restrict__ h, int* __restrict__ pidx,
    float* __restrict__ maskf, const int* __restrict__ coords,
    int* __restrict__ grid) {
  int n = blockIdx.x, t = threadIdx.x;
  float x = feats[(size_t)n * C + t];
  float4 w0 = *(const float4*)(sdw + t * 8);
  float4 w1 = *(const float4*)(sdw + t * 8 + 4);
  float v[10] = {x * w0.x, x * w0.y, x * w0.z, x * w0.w,
                 x * w1.x, x * w1.y, x * w1.z, x * w1.w, x, x * x};
#pragma unroll
  for (int mk = 1; mk < 64; mk <<= 1) {
#pragma unroll
    for (int j = 0; j < 10; ++j) v[j] += __shfl_xor(v[j], mk, 64);
  }
  __shared__ float red[4][10];
  int wave = t >> 6, lane = t & 63;
  if (lane == 0) {
#pragma unroll
    for (int j = 0; j < 10; ++j) red[wave][j] = v[j];
  }
  __syncthreads();
  float sums[10];
#pragma unroll
  for (int j = 0; j < 10; ++j)
    sums[j] = red[0][j] + red[1][j] + red[2][j] + red[3][j];
  float mean = sums[8] / (float)C;
  float var  = sums[9] / (float)C - mean * mean;
  float rstd = rsqrtf(var + EPS);
  if (t < 8) {
    float sd = sums[t] + sdb[t];
    out_subdiv[(size_t)n * 8 + t] = sd;
    bool mk = sd > 0.f;
    pidx[n * 8 + t]  = mk ? n : N;   // h/U row index (N = zero/skip row)
    maskf[n * 8 + t] = mk ? 1.f : 0.f;
    // scatter child id into lookup grid (grid pre-inited to M by k_prep)
    int xx = coords[n * 3 + 0] * 2 + ((t >> 2) & 1) + 1;
    int yy = coords[n * 3 + 1] * 2 + ((t >> 1) & 1) + 1;
    int zz = coords[n * 3 + 2] * 2 + (t & 1) + 1;
    grid[(xx * G + yy) * G + zz] = n * 8 + t;
  }
  float y  = (x - mean) * rstd * n1w[t] + n1b[t];
  float sl = y / (1.f + __expf(-y));
  h[(size_t)n * C + t] = f2bf(sl);
}

// ---- fused middle kernel: three independent roles after k_rownorm ----------
//   blocks [0, DG_BLK):            dense GEMM U = h @ w1t  (MFMA long pole)
//   blocks [DG_BLK, DG_BLK+NI_BLK): neighbor tables g1t / nidxt
//   blocks [.., +SK_BLK):           skip GEMM sres = feats @ skip_w + b
__global__ __launch_bounds__(256, 3) void k_mid(
    const unsigned short* __restrict__ src, const unsigned short* __restrict__ wt,
    float* __restrict__ U, const int* __restrict__ coords,
    const int* __restrict__ grid, const int* __restrict__ pidx,
    int* __restrict__ g1t, int* __restrict__ nidxt,
    const float* __restrict__ feats, const float* __restrict__ skw,
    const float* __restrict__ skb, float* __restrict__ sres) {
  const int b = blockIdx.x;
  if (b < DG_BLK) {
    // ---------------- dense GEMM role (CIN=256, NCB=8) ----------------------
    constexpr int CIN = C, NCB = 8;
    __shared__ unsigned short sA[2][128 * 32];
    __shared__ unsigned short sB[2][128 * 32];
    const int t = threadIdx.x;
    const int w = t >> 6, lane = t & 63;
    const int quad = lane >> 4, ln = lane & 15;
    const int m0 = (b & 15) * 128;         // N/128 = 16 row-blocks
    const int k = b >> 4;                  // tap index = 128-col block of U

    const int rh = (w >> 1) * 64, ch = (w & 1) * 64;
    const int row2 = t >> 1;
    const int c0 = (t & 1) * 2;
    const int x3 = (row2 >> 1) & 3;
    const int wsl0 = row2 * 32 + ((c0) ^ x3) * 8;
    const int wsl1 = row2 * 32 + ((c0 + 1) ^ x3) * 8;

    const unsigned short* pa_base = src + (size_t)(m0 + row2) * CIN + c0 * 8;
    const unsigned short* pb_base = wt + ((size_t)k * CO + row2) * CIN + c0 * 8;

    bf8 ra0, ra1, rb0, rb1;
    auto loadreg = [&](int s) {
      const unsigned short* pa = pa_base + s * 32;
      const unsigned short* pb = pb_base + s * 32;
      ra0 = *(const bf8*)(pa);
      ra1 = *(const bf8*)(pa + 8);
      rb0 = *(const bf8*)(pb);
      rb1 = *(const bf8*)(pb + 8);
    };
    auto writelds = [&](int buf) {
      *(bf8*)(sA[buf] + wsl0) = ra0;
      *(bf8*)(sA[buf] + wsl1) = ra1;
      *(bf8*)(sB[buf] + wsl0) = rb0;
      *(bf8*)(sB[buf] + wsl1) = rb1;
    };

    f4 acc[16];
    f4 zero = {0.f, 0.f, 0.f, 0.f};
#pragma unroll
    for (int i = 0; i < 16; ++i) acc[i] = zero;

    const int slot = (quad ^ ((ln >> 1) & 3)) * 8;

    loadreg(0);
    writelds(0);
    for (int s = 0; s < NCB; ++s) {
      const bool have = (s + 1 < NCB);
      if (have) loadreg(s + 1);
      __syncthreads();
      const unsigned short* pa = sA[s & 1];
      const unsigned short* pb = sB[s & 1];
      bf8 av[4], bv[4];
#pragma unroll
      for (int ti = 0; ti < 4; ++ti)
        av[ti] = *(const bf8*)(pa + (rh + ti * 16 + ln) * 32 + slot);
#pragma unroll
      for (int tj = 0; tj < 4; ++tj)
        bv[tj] = *(const bf8*)(pb + (ch + tj * 16 + ln) * 32 + slot);
#pragma unroll
      for (int ti = 0; ti < 4; ++ti)
#pragma unroll
        for (int tj = 0; tj < 4; ++tj)
          acc[ti * 4 + tj] = __builtin_amdgcn_mfma_f32_16x16x32_bf16(
              av[ti], bv[tj], acc[ti * 4 + tj], 0, 0, 0);
      if (have) writelds((s + 1) & 1);
    }

    // store f32: D layout col=ln, row=quad*4+rr; U row stride UW=3456
#pragma unroll
    for (int ti = 0; ti < 4; ++ti) {
      int mrow = rh + ti * 16 + quad * 4;
#pragma unroll
      for (int tj = 0; tj < 4; ++tj) {
        int co = ch + tj * 16 + ln;
#pragma unroll
        for (int rr = 0; rr < 4; ++rr)
          U[(size_t)(m0 + mrow + rr) * UW + k * CO + co] = acc[ti * 4 + tj][rr];
      }
    }
    return;
  }
  if (b < DG_BLK + NI_BLK) {
    // ---------------- nidx role: build g1t[k][m], nidxt[k][m] ---------------
    int idx = (b - DG_BLK) * 256 + threadIdx.x;   // [0, 27*M)
    int m = idx & (M - 1);          // M = 2^14
    int k = idx >> 14;
    int p = m >> 3, j = m & 7;
    int dx = k / 9 - 1;
    int dy = (k / 3) % 3 - 1;
    int dz = k % 3 - 1;
    int x = coords[p * 3 + 0] * 2 + ((j >> 2) & 1) + 1 + dx;
    int y = coords[p * 3 + 1] * 2 + ((j >> 1) & 1) + 1 + dy;
    int z = coords[p * 3 + 2] * 2 + (j & 1) + 1 + dz;
    int gv = grid[(x * G + y) * G + z];
    nidxt[idx] = gv;                      // index into h1 (M = zero row)
    g1t[idx] = (gv == M) ? N : pidx[gv];  // index into U  (N = skip/zero)
    return;
  }
  {
    // ---------------- skip role: sres = feats @ skip_w + skip_b -------------
    __shared__ float tile[32][36];
    int bb = b - DG_BLK - NI_BLK;
    int t = threadIdx.x;
    int rb = (bb >> 1) * 32;              // 32 rows per block
    int ob = (bb & 1) * 64;               // 64-col half
    int o = ob + (t & 63);
    int rg = (t >> 6) * 8;                // 8 rows per wave-group
    float acc[8] = {0, 0, 0, 0, 0, 0, 0, 0};
    for (int cb = 0; cb < C; cb += 32) {
      __syncthreads();
      int row = t >> 3, cc = (t & 7) * 4;
      *(float4*)&tile[row][cc] =
          *(const float4*)(feats + (size_t)(rb + row) * C + cb + cc);
      __syncthreads();
      for (int c = 0; c < 32; ++c) {
        float wv = skw[(size_t)(cb + c) * CO + o];
#pragma unroll
        for (int r = 0; r < 8; ++r) acc[r] += tile[rg + r][c] * wv;
      }
    }
    float bv = skb[o];
#pragma unroll
    for (int r = 0; r < 8; ++r) sres[(size_t)(rb + rg + r) * CO + o] = acc[r] + bv;
  }
}

// --- conv1 combine: out1[m] = sum_k U[g1t[k][m]][k*128+:] + b1; LN; silu -> h1
__global__ __launch_bounds__(256) void k_g1sum(
    const float* __restrict__ U, const int* __restrict__ g1t,
    const float* __restrict__ b1, unsigned short* __restrict__ h1) {
  int wave = threadIdx.x >> 6, lane = threadIdx.x & 63;
  int m = blockIdx.x * 4 + wave;
  float a0 = b1[2 * lane], a1 = b1[2 * lane + 1];
#pragma unroll
  for (int k = 0; k < 27; ++k) {
    int g = g1t[k * M + m];          // wave-uniform
    if (g < N) {
      float2 v = *(const float2*)(U + (size_t)g * UW + k * CO + 2 * lane);
      a0 += v.x; a1 += v.y;
    }
  }
  float sum = a0 + a1, sq = a0 * a0 + a1 * a1;
#pragma unroll
  for (int mk = 1; mk < 64; mk <<= 1) {
    sum += __shfl_xor(sum, mk, 64);
    sq  += __shfl_xor(sq, mk, 64);
  }
  float mean = sum / (float)CO;
  float var  = sq / (float)CO - mean * mean;
  float rstd = rsqrtf(var + EPS);
  float y0 = (a0 - mean) * rstd;
  float y1 = (a1 - mean) * rstd;
  float s0 = y0 / (1.f + __expf(-y0));
  float s1 = y1 / (1.f + __expf(-y1));
  *(ushort2*)(h1 + (size_t)m * CO + 2 * lane) = ushort2{f2bf(s0), f2bf(s1)};
}

// ---------------- implicit-GEMM conv (conv2): register-staged LDS pipeline ---
template <int CIN, int NCB, int KCH>
__global__ __launch_bounds__(256, 3) void k_conv(
    const unsigned short* __restrict__ src, const int* __restrict__ gt,
    const unsigned short* __restrict__ wt, unsigned short* __restrict__ part) {
  __shared__ unsigned short sA[2][128 * 32];   // 8 KB per buf
  __shared__ unsigned short sB[2][128 * 32];
  const int t = threadIdx.x;
  const int w = t >> 6, lane = t & 63;
  const int quad = lane >> 4, ln = lane & 15;
  const int m0 = blockIdx.x * 128;
  const int kpart = blockIdx.y;
  const int k0 = kpart * KCH;
  const int nk = min(KCH, 27 - k0);
  const int nstage = nk * NCB;
  const int rh = (w >> 1) * 64, ch = (w & 1) * 64;

  const int row2 = t >> 1;
  const int c0 = (t & 1) * 2;
  const int x3 = (row2 >> 1) & 3;
  const int wsl0 = row2 * 32 + ((c0) ^ x3) * 8;
  const int wsl1 = row2 * 32 + ((c0 + 1) ^ x3) * 8;

  int ga[KCH];
#pragma unroll
  for (int kk = 0; kk < KCH; ++kk)
    ga[kk] = (kk < nk) ? gt[(size_t)(k0 + kk) * M + m0 + row2] : 0;

  bf8 ra0, ra1, rb0, rb1;
  auto loadreg = [&](int s) {
    const int kk = s / NCB;
    const int cb = s - kk * NCB;
    const unsigned short* pa = src + (size_t)ga[kk] * CIN + cb * 32 + c0 * 8;
    const unsigned short* pb =
        wt + ((size_t)(k0 + kk) * CO + row2) * CIN + cb * 32 + c0 * 8;
    ra0 = *(const bf8*)(pa);
    ra1 = *(const bf8*)(pa + 8);
    rb0 = *(const bf8*)(pb);
    rb1 = *(const bf8*)(pb + 8);
  };
  auto writelds = [&](int buf) {
    *(bf8*)(sA[buf] + wsl0) = ra0;
    *(bf8*)(sA[buf] + wsl1) = ra1;
    *(bf8*)(sB[buf] + wsl0) = rb0;
    *(bf8*)(sB[buf] + wsl1) = rb1;
  };

  f4 acc[16];
  f4 zero = {0.f, 0.f, 0.f, 0.f};
#pragma unroll
  for (int i = 0; i < 16; ++i) acc[i] = zero;

  const int slot = (quad ^ ((ln >> 1) & 3)) * 8;

  loadreg(0);
  writelds(0);
  for (int s = 0; s < nstage; ++s) {
    const bool have = (s + 1 < nstage);
    if (have) loadreg(s + 1);
    __syncthreads();
    const unsigned short* pa = sA[s & 1];
    const unsigned short* pb = sB[s & 1];
    bf8 av[4], bv[4];
#pragma unroll
    for (int ti = 0; ti < 4; ++ti)
      av[ti] = *(const bf8*)(pa + (rh + ti * 16 + ln) * 32 + slot);
#pragma unroll
    for (int tj = 0; tj < 4; ++tj)
      bv[tj] = *(const bf8*)(pb + (ch + tj * 16 + ln) * 32 + slot);
#pragma unroll
    for (int ti = 0; ti < 4; ++ti)
#pragma unroll
      for (int tj = 0; tj < 4; ++tj)
        acc[ti * 4 + tj] = __builtin_amdgcn_mfma_f32_16x16x32_bf16(
            av[ti], bv[tj], acc[ti * 4 + tj], 0, 0, 0);
    if (have) writelds((s + 1) & 1);
  }

  unsigned short* pp = part + ((size_t)kpart * M + m0) * CO;
#pragma unroll
  for (int ti = 0; ti < 4; ++ti) {
    int mrow = rh + ti * 16 + quad * 4;
#pragma unroll
    for (int tj = 0; tj < 4; ++tj) {
      int co = ch + tj * 16 + ln;
#pragma unroll
      for (int rr = 0; rr < 4; ++rr)
        pp[(size_t)(mrow + rr) * CO + co] = f2bf(acc[ti * 4 + tj][rr]);
    }
  }
}

// ---------------- reduce 2: sum KP2 bf16 partials + bias + skip, *mask -> out
__global__ __launch_bounds__(256) void k_r2(const unsigned short* __restrict__ p,
                                            const float* __restrict__ bias,
                                            const float* __restrict__ sres,
                                            const float* __restrict__ maskf,
                                            float* __restrict__ out) {
  int i = blockIdx.x * 256 + threadIdx.x;   // i in [0, M*CO/4)
  int m = i >> 5;                            // 32 groups of 4 per row
  int o4 = (i & 31) * 4;
  float4 acc = *(const float4*)(bias + o4);
#pragma unroll
  for (int q = 0; q < KP2; ++q) {
    ushort4 a = *(const ushort4*)(p + ((size_t)q * M + m) * CO + o4);
    acc.x += bf2f(a.x); acc.y += bf2f(a.y);
    acc.z += bf2f(a.z); acc.w += bf2f(a.w);
  }
  float4 s = *(const float4*)(sres + (size_t)(m >> 3) * CO + o4);
  float mk = maskf[m];
  float4 r;
  r.x = (acc.x + s.x) * mk;
  r.y = (acc.y + s.y) * mk;
  r.z = (acc.z + s.z) * mk;
  r.w = (acc.w + s.w) * mk;
  *(float4*)(out + (size_t)m * CO + o4) = r;
}

// ---------------- launcher ----------------------------------------------------
extern "C" void kernel_launch(void* const* d_in, const int* in_sizes, int n_in,
                              void* d_out, int out_size, void* d_ws, size_t ws_size,
                              hipStream_t stream) {
  const float* feats = (const float*)d_in[0];
  const float* n1w   = (const float*)d_in[1];
  const float* n1b   = (const float*)d_in[2];
  const float* sdw   = (const float*)d_in[3];
  const float* sdb   = (const float*)d_in[4];
  const float* c1w   = (const float*)d_in[5];
  const float* c1b   = (const float*)d_in[6];
  const float* c2w   = (const float*)d_in[7];
  const float* c2b   = (const float*)d_in[8];
  const float* skw   = (const float*)d_in[9];
  const float* skb   = (const float*)d_in[10];
  const int* coords  = (const int*)d_in[11];
  float* out = (float*)d_out;   // [M*CO] conv output, then [N*8] subdiv

  char* ws = (char*)d_ws;
  size_t off = 0;
  auto alloc = [&](size_t bytes) -> char* {
    char* p = ws + off;
    off += (bytes + 255) & ~(size_t)255;
    return p;
  };
  unsigned short* h    = (unsigned short*)alloc((size_t)(N + 1) * C * 2);
  unsigned short* h1   = (unsigned short*)alloc((size_t)(M + 1) * CO * 2);
  int*   grid  = (int*)alloc((size_t)G * G * G * 4);
  int*   nidxt = (int*)alloc((size_t)27 * M * 4);
  int*   g1t   = (int*)alloc((size_t)27 * M * 4);
  int*   pidx  = (int*)alloc((size_t)M * 4);
  float* maskf = (float*)alloc((size_t)M * 4);
  float* sres  = (float*)alloc((size_t)N * CO * 4);
  unsigned short* w1t = (unsigned short*)alloc((size_t)27 * CO * C * 2);
  unsigned short* w2t = (unsigned short*)alloc((size_t)27 * CO * CO * 2);
  float* U = (float*)alloc((size_t)N * UW * 4);                 // 28.3 MB
  unsigned short* pc  = (unsigned short*)alloc((size_t)KP2 * M * CO * 2);

  k_prep<<<(27 * C * CO + 255) / 256, 256, 0, stream>>>(grid, h, h1, c1w, w1t,
                                                        c2w, w2t);
  k_rownorm<<<N, 256, 0, stream>>>(feats, n1w, n1b, sdw, sdb,
                                   out + (size_t)M * CO, h, pidx, maskf,
                                   coords, grid);
  // fused: dense U-GEMM (MFMA) + neighbor tables + skip GEMM, concurrent
  k_mid<<<DG_BLK + NI_BLK + SK_BLK, 256, 0, stream>>>(
      h, w1t, U, coords, grid, pidx, g1t, nidxt, feats, skw, skb, sres);
  // gather-add over 27 taps, fused bias + LN + silu -> h1
  k_g1sum<<<M / 4, 256, 0, stream>>>(U, g1t, c1b, h1);
  // conv2: implicit GEMM, CIN=128 (4 chunks of 32), k-split 4x7
  k_conv<CO, 4, KCHUNK2><<<dim3(M / 128, KP2), 256, 0, stream>>>(h1, nidxt,
                                                                 w2t, pc);
  k_r2<<<M * CO / 4 / 256, 256, 0, stream>>>(pc, c2b, sres, maskf, out);
}

// Round 6
// 179.050 us; speedup vs baseline: 1.0784x; 1.0214x over previous
//
#include <hip/hip_runtime.h>
#include <cstdint>
#include <cstddef>

// Problem constants (from reference)
constexpr int N  = 2048;     // parents
constexpr int C  = 256;      // in channels
constexpr int CO = 128;      // out channels
constexpr int M  = 16384;    // children (8*N)
constexpr int G  = 66;       // padded child grid dim (S2+2)
constexpr int KP2 = 4;       // k-split parts for conv2
constexpr int KCHUNK2 = 7;   // neighbors per part (7,7,7,6)
constexpr int UW = 27 * CO;  // U row width = 3456
constexpr float EPS = 1e-6f;

using bf8 = __attribute__((ext_vector_type(8))) short;   // 8 bf16 (4 VGPRs)
using f4  = __attribute__((ext_vector_type(4))) float;   // 4 f32 acc

static __device__ __forceinline__ unsigned short f2bf(float f) {
  unsigned u = __float_as_uint(f);
  u += 0x7fffu + ((u >> 16) & 1u);     // round-to-nearest-even
  return (unsigned short)(u >> 16);
}
static __device__ __forceinline__ float bf2f(unsigned short s) {
  return __uint_as_float((unsigned)s << 16);
}

// ---------------- prep: grid sentinel + zero rows + both weight transposes ---
__global__ void k_prep(int* __restrict__ grid, unsigned short* __restrict__ h,
                       unsigned short* __restrict__ h1,
                       const float* __restrict__ c1w, unsigned short* __restrict__ w1t,
                       const float* __restrict__ c2w, unsigned short* __restrict__ w2t) {
  int i = blockIdx.x * 256 + threadIdx.x;
  if (i < G * G * G) grid[i] = M;
  if (i < C)  h[(size_t)N * C + i] = 0;
  if (i < CO) h1[(size_t)M * CO + i] = 0;
  if (i < 27 * C * CO) {       // w1t[k][o][c] = c1w[k][c][o]
    int c = i % C;
    int rest = i / C;
    int o = rest % CO;
    int k = rest / CO;
    w1t[i] = f2bf(c1w[((size_t)(k * C + c)) * CO + o]);
  }
  if (i < 27 * CO * CO) {      // w2t[k][o][c] = c2w[k][c][o]
    int c = i % CO;
    int rest = i / CO;
    int o = rest % CO;
    int k = rest / CO;
    w2t[i] = f2bf(c2w[((size_t)(k * CO + c)) * CO + o]);
  }
}

// ------- per-parent: subdiv + mask + LN + silu -> h (bf16); + child scatter --
__global__ __launch_bounds__(256) void k_rownorm(
    const float* __restrict__ feats, const float* __restrict__ n1w,
    const float* __restrict__ n1b, const float* __restrict__ sdw,
    const float* __restrict__ sdb, float* __restrict__ out_subdiv,
    unsigned short* __restrict__ h, int* __restrict__ pidx,
    float* __restrict__ maskf, const int* __restrict__ coords,
    int* __restrict__ grid) {
  int n = blockIdx.x, t = threadIdx.x;
  float x = feats[(size_t)n * C + t];
  float4 w0 = *(const float4*)(sdw + t * 8);
  float4 w1 = *(const float4*)(sdw + t * 8 + 4);
  float v[10] = {x * w0.x, x * w0.y, x * w0.z, x * w0.w,
                 x * w1.x, x * w1.y, x * w1.z, x * w1.w, x, x * x};
#pragma unroll
  for (int mk = 1; mk < 64; mk <<= 1) {
#pragma unroll
    for (int j = 0; j < 10; ++j) v[j] += __shfl_xor(v[j], mk, 64);
  }
  __shared__ float red[4][10];
  int wave = t >> 6, lane = t & 63;
  if (lane == 0) {
#pragma unroll
    for (int j = 0; j < 10; ++j) red[wave][j] = v[j];
  }
  __syncthreads();
  float sums[10];
#pragma unroll
  for (int j = 0; j < 10; ++j)
    sums[j] = red[0][j] + red[1][j] + red[2][j] + red[3][j];
  float mean = sums[8] / (float)C;
  float var  = sums[9] / (float)C - mean * mean;
  float rstd = rsqrtf(var + EPS);
  if (t < 8) {
    float sd = sums[t] + sdb[t];
    out_subdiv[(size_t)n * 8 + t] = sd;
    bool mk = sd > 0.f;
    pidx[n * 8 + t]  = mk ? n : N;   // h/U row index (N = zero/skip row)
    maskf[n * 8 + t] = mk ? 1.f : 0.f;
    // scatter child id into lookup grid (grid pre-inited to M by k_prep)
    int xx = coords[n * 3 + 0] * 2 + ((t >> 2) & 1) + 1;
    int yy = coords[n * 3 + 1] * 2 + ((t >> 1) & 1) + 1;
    int zz = coords[n * 3 + 2] * 2 + (t & 1) + 1;
    grid[(xx * G + yy) * G + zz] = n * 8 + t;
  }
  float y  = (x - mean) * rstd * n1w[t] + n1b[t];
  float sl = y / (1.f + __expf(-y));
  h[(size_t)n * C + t] = f2bf(sl);
}

// ---------------- build transposed tables nidxt[k][M], g1t[k][M] -------------
__global__ void k_nidx(const int* __restrict__ coords, const int* __restrict__ grid,
                       const int* __restrict__ pidx, int* __restrict__ nidxt,
                       int* __restrict__ g1t) {
  int idx = blockIdx.x * 256 + threadIdx.x;
  if (idx >= M * 27) return;
  int m = idx & (M - 1);          // M = 2^14
  int k = idx >> 14;
  int p = m >> 3, j = m & 7;
  int dx = k / 9 - 1;
  int dy = (k / 3) % 3 - 1;
  int dz = k % 3 - 1;
  int x = coords[p * 3 + 0] * 2 + ((j >> 2) & 1) + 1 + dx;
  int y = coords[p * 3 + 1] * 2 + ((j >> 1) & 1) + 1 + dy;
  int z = coords[p * 3 + 2] * 2 + (j & 1) + 1 + dz;
  int gv = grid[(x * G + y) * G + z];
  nidxt[idx] = gv;                      // index into h1 (M = zero row)
  g1t[idx] = (gv == M) ? N : pidx[gv];  // index into U  (N = skip/zero)
}

// ---------------- skip GEMM: s = feats @ skip_w + skip_b  (f32) --------------
__global__ __launch_bounds__(256) void k_skip(const float* __restrict__ feats,
                                              const float* __restrict__ skw,
                                              const float* __restrict__ skb,
                                              float* __restrict__ s) {
  __shared__ float tile[32][36];
  int t = threadIdx.x;
  int rb = (blockIdx.x >> 1) * 32;        // 32 rows per block
  int ob = (blockIdx.x & 1) * 64;         // 64-col half
  int o = ob + (t & 63);
  int rg = (t >> 6) * 8;                  // 8 rows per wave-group
  float acc[8] = {0, 0, 0, 0, 0, 0, 0, 0};
  for (int cb = 0; cb < C; cb += 32) {
    __syncthreads();
    int row = t >> 3, cc = (t & 7) * 4;
    *(float4*)&tile[row][cc] =
        *(const float4*)(feats + (size_t)(rb + row) * C + cb + cc);
    __syncthreads();
    for (int c = 0; c < 32; ++c) {
      float wv = skw[(size_t)(cb + c) * CO + o];
#pragma unroll
      for (int r = 0; r < 8; ++r) acc[r] += tile[rg + r][c] * wv;
    }
  }
  float bv = skb[o];
#pragma unroll
  for (int r = 0; r < 8; ++r) s[(size_t)(rb + rg + r) * CO + o] = acc[r] + bv;
}

// ---------------- dense GEMM: U[n][k*128+o] = h[n][:] . w1t[k][o][:]  --------
// Output U stored as bf16 (halves write traffic; rounding at single-tap
// granularity, smaller than the original k-split bf16 partials).
template <int CIN, int NCB>
__global__ __launch_bounds__(256, 3) void k_dgemm(
    const unsigned short* __restrict__ src, const unsigned short* __restrict__ wt,
    unsigned short* __restrict__ U) {
  __shared__ unsigned short sA[2][128 * 32];
  __shared__ unsigned short sB[2][128 * 32];
  const int t = threadIdx.x;
  const int w = t >> 6, lane = t & 63;
  const int quad = lane >> 4, ln = lane & 15;
  const int m0 = blockIdx.x * 128;
  const int k = blockIdx.y;                  // tap index = 128-col block of U
  const int rh = (w >> 1) * 64, ch = (w & 1) * 64;

  const int row2 = t >> 1;
  const int c0 = (t & 1) * 2;
  const int x3 = (row2 >> 1) & 3;
  const int wsl0 = row2 * 32 + ((c0) ^ x3) * 8;
  const int wsl1 = row2 * 32 + ((c0 + 1) ^ x3) * 8;

  const unsigned short* pa_base = src + (size_t)(m0 + row2) * CIN + c0 * 8;
  const unsigned short* pb_base =
      wt + ((size_t)k * CO + row2) * CIN + c0 * 8;

  bf8 ra0, ra1, rb0, rb1;
  auto loadreg = [&](int s) {
    const unsigned short* pa = pa_base + s * 32;
    const unsigned short* pb = pb_base + s * 32;
    ra0 = *(const bf8*)(pa);
    ra1 = *(const bf8*)(pa + 8);
    rb0 = *(const bf8*)(pb);
    rb1 = *(const bf8*)(pb + 8);
  };
  auto writelds = [&](int buf) {
    *(bf8*)(sA[buf] + wsl0) = ra0;
    *(bf8*)(sA[buf] + wsl1) = ra1;
    *(bf8*)(sB[buf] + wsl0) = rb0;
    *(bf8*)(sB[buf] + wsl1) = rb1;
  };

  f4 acc[16];
  f4 zero = {0.f, 0.f, 0.f, 0.f};
#pragma unroll
  for (int i = 0; i < 16; ++i) acc[i] = zero;

  const int slot = (quad ^ ((ln >> 1) & 3)) * 8;

  loadreg(0);
  writelds(0);
  for (int s = 0; s < NCB; ++s) {
    const bool have = (s + 1 < NCB);
    if (have) loadreg(s + 1);
    __syncthreads();
    const unsigned short* pa = sA[s & 1];
    const unsigned short* pb = sB[s & 1];
    bf8 av[4], bv[4];
#pragma unroll
    for (int ti = 0; ti < 4; ++ti)
      av[ti] = *(const bf8*)(pa + (rh + ti * 16 + ln) * 32 + slot);
#pragma unroll
    for (int tj = 0; tj < 4; ++tj)
      bv[tj] = *(const bf8*)(pb + (ch + tj * 16 + ln) * 32 + slot);
#pragma unroll
    for (int ti = 0; ti < 4; ++ti)
#pragma unroll
      for (int tj = 0; tj < 4; ++tj)
        acc[ti * 4 + tj] = __builtin_amdgcn_mfma_f32_16x16x32_bf16(
            av[ti], bv[tj], acc[ti * 4 + tj], 0, 0, 0);
    if (have) writelds((s + 1) & 1);
  }

  // store bf16: D layout col=ln, row=quad*4+rr; U row stride UW=3456
#pragma unroll
  for (int ti = 0; ti < 4; ++ti) {
    int mrow = rh + ti * 16 + quad * 4;
#pragma unroll
    for (int tj = 0; tj < 4; ++tj) {
      int co = ch + tj * 16 + ln;
#pragma unroll
      for (int rr = 0; rr < 4; ++rr)
        U[(size_t)(m0 + mrow + rr) * UW + k * CO + co] =
            f2bf(acc[ti * 4 + tj][rr]);
    }
  }
}

// --- conv1 combine: out1[m] = sum_k U[g1t[k][m]][k*128+:] + b1; LN; silu -> h1
// One wave per child row m. g1t == N (missing/masked neighbor) -> skip read.
__global__ __launch_bounds__(256) void k_g1sum(
    const unsigned short* __restrict__ U, const int* __restrict__ g1t,
    const float* __restrict__ b1, unsigned short* __restrict__ h1) {
  int wave = threadIdx.x >> 6, lane = threadIdx.x & 63;
  int m = blockIdx.x * 4 + wave;
  float a0 = b1[2 * lane], a1 = b1[2 * lane + 1];
#pragma unroll
  for (int k = 0; k < 27; ++k) {
    int g = g1t[k * M + m];          // wave-uniform
    if (g < N) {
      ushort2 v = *(const ushort2*)(U + (size_t)g * UW + k * CO + 2 * lane);
      a0 += bf2f(v.x); a1 += bf2f(v.y);
    }
  }
  float sum = a0 + a1, sq = a0 * a0 + a1 * a1;
#pragma unroll
  for (int mk = 1; mk < 64; mk <<= 1) {
    sum += __shfl_xor(sum, mk, 64);
    sq  += __shfl_xor(sq, mk, 64);
  }
  float mean = sum / (float)CO;
  float var  = sq / (float)CO - mean * mean;
  float rstd = rsqrtf(var + EPS);
  float y0 = (a0 - mean) * rstd;
  float y1 = (a1 - mean) * rstd;
  float s0 = y0 / (1.f + __expf(-y0));
  float s1 = y1 / (1.f + __expf(-y1));
  *(ushort2*)(h1 + (size_t)m * CO + 2 * lane) = ushort2{f2bf(s0), f2bf(s1)};
}

// ---------------- implicit-GEMM conv (conv2): register-staged LDS pipeline ---
template <int CIN, int NCB, int KCH>
__global__ __launch_bounds__(256, 3) void k_conv(
    const unsigned short* __restrict__ src, const int* __restrict__ gt,
    const unsigned short* __restrict__ wt, unsigned short* __restrict__ part) {
  __shared__ unsigned short sA[2][128 * 32];   // 8 KB per buf
  __shared__ unsigned short sB[2][128 * 32];
  const int t = threadIdx.x;
  const int w = t >> 6, lane = t & 63;
  const int quad = lane >> 4, ln = lane & 15;
  const int m0 = blockIdx.x * 128;
  const int kpart = blockIdx.y;
  const int k0 = kpart * KCH;
  const int nk = min(KCH, 27 - k0);
  const int nstage = nk * NCB;
  const int rh = (w >> 1) * 64, ch = (w & 1) * 64;

  const int row2 = t >> 1;
  const int c0 = (t & 1) * 2;
  const int x3 = (row2 >> 1) & 3;
  const int wsl0 = row2 * 32 + ((c0) ^ x3) * 8;
  const int wsl1 = row2 * 32 + ((c0 + 1) ^ x3) * 8;

  int ga[KCH];
#pragma unroll
  for (int kk = 0; kk < KCH; ++kk)
    ga[kk] = (kk < nk) ? gt[(size_t)(k0 + kk) * M + m0 + row2] : 0;

  bf8 ra0, ra1, rb0, rb1;
  auto loadreg = [&](int s) {
    const int kk = s / NCB;
    const int cb = s - kk * NCB;
    const unsigned short* pa = src + (size_t)ga[kk] * CIN + cb * 32 + c0 * 8;
    const unsigned short* pb =
        wt + ((size_t)(k0 + kk) * CO + row2) * CIN + cb * 32 + c0 * 8;
    ra0 = *(const bf8*)(pa);
    ra1 = *(const bf8*)(pa + 8);
    rb0 = *(const bf8*)(pb);
    rb1 = *(const bf8*)(pb + 8);
  };
  auto writelds = [&](int buf) {
    *(bf8*)(sA[buf] + wsl0) = ra0;
    *(bf8*)(sA[buf] + wsl1) = ra1;
    *(bf8*)(sB[buf] + wsl0) = rb0;
    *(bf8*)(sB[buf] + wsl1) = rb1;
  };

  f4 acc[16];
  f4 zero = {0.f, 0.f, 0.f, 0.f};
#pragma unroll
  for (int i = 0; i < 16; ++i) acc[i] = zero;

  const int slot = (quad ^ ((ln >> 1) & 3)) * 8;

  loadreg(0);
  writelds(0);
  for (int s = 0; s < nstage; ++s) {
    const bool have = (s + 1 < nstage);
    if (have) loadreg(s + 1);
    __syncthreads();
    const unsigned short* pa = sA[s & 1];
    const unsigned short* pb = sB[s & 1];
    bf8 av[4], bv[4];
#pragma unroll
    for (int ti = 0; ti < 4; ++ti)
      av[ti] = *(const bf8*)(pa + (rh + ti * 16 + ln) * 32 + slot);
#pragma unroll
    for (int tj = 0; tj < 4; ++tj)
      bv[tj] = *(const bf8*)(pb + (ch + tj * 16 + ln) * 32 + slot);
#pragma unroll
    for (int ti = 0; ti < 4; ++ti)
#pragma unroll
      for (int tj = 0; tj < 4; ++tj)
        acc[ti * 4 + tj] = __builtin_amdgcn_mfma_f32_16x16x32_bf16(
            av[ti], bv[tj], acc[ti * 4 + tj], 0, 0, 0);
    if (have) writelds((s + 1) & 1);
  }

  unsigned short* pp = part + ((size_t)kpart * M + m0) * CO;
#pragma unroll
  for (int ti = 0; ti < 4; ++ti) {
    int mrow = rh + ti * 16 + quad * 4;
#pragma unroll
    for (int tj = 0; tj < 4; ++tj) {
      int co = ch + tj * 16 + ln;
#pragma unroll
      for (int rr = 0; rr < 4; ++rr)
        pp[(size_t)(mrow + rr) * CO + co] = f2bf(acc[ti * 4 + tj][rr]);
    }
  }
}

// ---------------- reduce 2: sum KP2 bf16 partials + bias + skip, *mask -> out
__global__ __launch_bounds__(256) void k_r2(const unsigned short* __restrict__ p,
                                            const float* __restrict__ bias,
                                            const float* __restrict__ sres,
                                            const float* __restrict__ maskf,
                                            float* __restrict__ out) {
  int i = blockIdx.x * 256 + threadIdx.x;   // i in [0, M*CO/4)
  int m = i >> 5;                            // 32 groups of 4 per row
  int o4 = (i & 31) * 4;
  float4 acc = *(const float4*)(bias + o4);
#pragma unroll
  for (int q = 0; q < KP2; ++q) {
    ushort4 a = *(const ushort4*)(p + ((size_t)q * M + m) * CO + o4);
    acc.x += bf2f(a.x); acc.y += bf2f(a.y);
    acc.z += bf2f(a.z); acc.w += bf2f(a.w);
  }
  float4 s = *(const float4*)(sres + (size_t)(m >> 3) * CO + o4);
  float mk = maskf[m];
  float4 r;
  r.x = (acc.x + s.x) * mk;
  r.y = (acc.y + s.y) * mk;
  r.z = (acc.z + s.z) * mk;
  r.w = (acc.w + s.w) * mk;
  *(float4*)(out + (size_t)m * CO + o4) = r;
}

// ---------------- launcher ----------------------------------------------------
extern "C" void kernel_launch(void* const* d_in, const int* in_sizes, int n_in,
                              void* d_out, int out_size, void* d_ws, size_t ws_size,
                              hipStream_t stream) {
  const float* feats = (const float*)d_in[0];
  const float* n1w   = (const float*)d_in[1];
  const float* n1b   = (const float*)d_in[2];
  const float* sdw   = (const float*)d_in[3];
  const float* sdb   = (const float*)d_in[4];
  const float* c1w   = (const float*)d_in[5];
  const float* c1b   = (const float*)d_in[6];
  const float* c2w   = (const float*)d_in[7];
  const float* c2b   = (const float*)d_in[8];
  const float* skw   = (const float*)d_in[9];
  const float* skb   = (const float*)d_in[10];
  const int* coords  = (const int*)d_in[11];
  float* out = (float*)d_out;   // [M*CO] conv output, then [N*8] subdiv

  char* ws = (char*)d_ws;
  size_t off = 0;
  auto alloc = [&](size_t bytes) -> char* {
    char* p = ws + off;
    off += (bytes + 255) & ~(size_t)255;
    return p;
  };
  unsigned short* h    = (unsigned short*)alloc((size_t)(N + 1) * C * 2);
  unsigned short* h1   = (unsigned short*)alloc((size_t)(M + 1) * CO * 2);
  int*   grid  = (int*)alloc((size_t)G * G * G * 4);
  int*   nidxt = (int*)alloc((size_t)27 * M * 4);
  int*   g1t   = (int*)alloc((size_t)27 * M * 4);
  int*   pidx  = (int*)alloc((size_t)M * 4);
  float* maskf = (float*)alloc((size_t)M * 4);
  float* sres  = (float*)alloc((size_t)N * CO * 4);
  unsigned short* w1t = (unsigned short*)alloc((size_t)27 * CO * C * 2);
  unsigned short* w2t = (unsigned short*)alloc((size_t)27 * CO * CO * 2);
  unsigned short* U = (unsigned short*)alloc((size_t)N * UW * 2);   // 14.2 MB bf16
  unsigned short* pc  = (unsigned short*)alloc((size_t)KP2 * M * CO * 2);

  k_prep<<<(27 * C * CO + 255) / 256, 256, 0, stream>>>(grid, h, h1, c1w, w1t,
                                                        c2w, w2t);
  k_rownorm<<<N, 256, 0, stream>>>(feats, n1w, n1b, sdw, sdb,
                                   out + (size_t)M * CO, h, pidx, maskf,
                                   coords, grid);
  k_nidx<<<(M * 27 + 255) / 256, 256, 0, stream>>>(coords, grid, pidx, nidxt, g1t);
  k_skip<<<128, 256, 0, stream>>>(feats, skw, skb, sres);

  // conv1 via factorization: dense U-GEMM (2048 x 3456 x 256), bf16 output ...
  k_dgemm<C, 8><<<dim3(N / 128, 27), 256, 0, stream>>>(h, w1t, U);
  // ... then gather-add over 27 taps, fused bias + LN + silu -> h1
  k_g1sum<<<M / 4, 256, 0, stream>>>(U, g1t, c1b, h1);

  // conv2: implicit GEMM, CIN=128 (4 chunks of 32), k-split 4x7
  k_conv<CO, 4, KCHUNK2><<<dim3(M / 128, KP2), 256, 0, stream>>>(h1, nidxt,
                                                                 w2t, pc);
  k_r2<<<M * CO / 4 / 256, 256, 0, stream>>>(pc, c2b, sres, maskf, out);
}

// Round 7
// 177.633 us; speedup vs baseline: 1.0870x; 1.0080x over previous
//
#include <hip/hip_runtime.h>
#include <cstdint>
#include <cstddef>

// Problem constants (from reference)
constexpr int N  = 2048;     // parents
constexpr int C  = 256;      // in channels
constexpr int CO = 128;      // out channels
constexpr int M  = 16384;    // children (8*N)
constexpr int G  = 66;       // padded child grid dim (S2+2)
constexpr int KP2 = 4;       // k-split parts for conv2
constexpr int KCHUNK2 = 7;   // neighbors per part (7,7,7,6)
constexpr int UW = 27 * CO;  // U row width = 3456
constexpr float EPS = 1e-6f;

using bf8 = __attribute__((ext_vector_type(8))) short;   // 8 bf16 (4 VGPRs)
using f4  = __attribute__((ext_vector_type(4))) float;   // 4 f32 acc

static __device__ __forceinline__ unsigned short f2bf(float f) {
  unsigned u = __float_as_uint(f);
  u += 0x7fffu + ((u >> 16) & 1u);     // round-to-nearest-even
  return (unsigned short)(u >> 16);
}
static __device__ __forceinline__ float bf2f(unsigned short s) {
  return __uint_as_float((unsigned)s << 16);
}

// ---------------- prep: grid/nidxtc sentinels + zero rows + weight transposes
__global__ void k_prep(int* __restrict__ grid, unsigned short* __restrict__ h,
                       unsigned short* __restrict__ h1,
                       const float* __restrict__ c1w, unsigned short* __restrict__ w1t,
                       const float* __restrict__ c2w, unsigned short* __restrict__ w2t,
                       int* __restrict__ nidxtc) {
  int i = blockIdx.x * 256 + threadIdx.x;
  if (i < G * G * G) grid[i] = M;
  if (i < 27 * M) nidxtc[i] = M;       // sentinel: h1 zero row (covers pad rows)
  if (i < C)  h[(size_t)N * C + i] = 0;
  if (i < CO) h1[(size_t)M * CO + i] = 0;
  if (i < 27 * C * CO) {       // w1t[k][o][c] = c1w[k][c][o]
    int c = i % C;
    int rest = i / C;
    int o = rest % CO;
    int k = rest / CO;
    w1t[i] = f2bf(c1w[((size_t)(k * C + c)) * CO + o]);
  }
  if (i < 27 * CO * CO) {      // w2t[k][o][c] = c2w[k][c][o]
    int c = i % CO;
    int rest = i / CO;
    int o = rest % CO;
    int k = rest / CO;
    w2t[i] = f2bf(c2w[((size_t)(k * CO + c)) * CO + o]);
  }
}

// ------- per-parent: subdiv + mask + LN + silu -> h (bf16); + child scatter --
// Emits per-parent 8-bit child mask (no atomics).
__global__ __launch_bounds__(256) void k_rownorm(
    const float* __restrict__ feats, const float* __restrict__ n1w,
    const float* __restrict__ n1b, const float* __restrict__ sdw,
    const float* __restrict__ sdb, float* __restrict__ out_subdiv,
    unsigned short* __restrict__ h, int* __restrict__ pidx,
    int* __restrict__ mbits, const int* __restrict__ coords,
    int* __restrict__ grid) {
  int n = blockIdx.x, t = threadIdx.x;
  float x = feats[(size_t)n * C + t];
  float4 w0 = *(const float4*)(sdw + t * 8);
  float4 w1 = *(const float4*)(sdw + t * 8 + 4);
  float v[10] = {x * w0.x, x * w0.y, x * w0.z, x * w0.w,
                 x * w1.x, x * w1.y, x * w1.z, x * w1.w, x, x * x};
#pragma unroll
  for (int mk = 1; mk < 64; mk <<= 1) {
#pragma unroll
    for (int j = 0; j < 10; ++j) v[j] += __shfl_xor(v[j], mk, 64);
  }
  __shared__ float red[4][10];
  int wave = t >> 6, lane = t & 63;
  if (lane == 0) {
#pragma unroll
    for (int j = 0; j < 10; ++j) red[wave][j] = v[j];
  }
  __syncthreads();
  float sums[10];
#pragma unroll
  for (int j = 0; j < 10; ++j)
    sums[j] = red[0][j] + red[1][j] + red[2][j] + red[3][j];
  float mean = sums[8] / (float)C;
  float var  = sums[9] / (float)C - mean * mean;
  float rstd = rsqrtf(var + EPS);
  bool mk = false;
  if (t < 8) {
    float sd = sums[t] + sdb[t];
    out_subdiv[(size_t)n * 8 + t] = sd;
    mk = sd > 0.f;
    pidx[n * 8 + t] = mk ? n : N;    // h/U row index (N = zero/skip row)
    // scatter child id into lookup grid (grid pre-inited to M by k_prep)
    int xx = coords[n * 3 + 0] * 2 + ((t >> 2) & 1) + 1;
    int yy = coords[n * 3 + 1] * 2 + ((t >> 1) & 1) + 1;
    int zz = coords[n * 3 + 2] * 2 + (t & 1) + 1;
    grid[(xx * G + yy) * G + zz] = n * 8 + t;
  }
  unsigned long long bal = __ballot(mk);   // wave 0 bits 0..7 = child mask
  if (t == 0) mbits[n] = (int)(bal & 0xffu);
  float y  = (x - mean) * rstd * n1w[t] + n1b[t];
  float sl = y / (1.f + __expf(-y));
  h[(size_t)n * C + t] = f2bf(sl);
}

// ---- deterministic prefix scan over per-parent popcounts -> pofs, nact ------
__global__ __launch_bounds__(256) void k_scan(const int* __restrict__ mbits,
                                              int* __restrict__ pofs,
                                              int* __restrict__ nact) {
  int t = threadIdx.x;
  int base = t * 8;                    // 256 threads x 8 parents = 2048
  int c[8];
  int s = 0;
#pragma unroll
  for (int i = 0; i < 8; ++i) { c[i] = s; s += __popc(mbits[base + i]); }
  int lane = t & 63, wave = t >> 6;
  int incl = s;
#pragma unroll
  for (int d = 1; d < 64; d <<= 1) {
    int vup = __shfl_up(incl, d, 64);
    if (lane >= d) incl += vup;
  }
  __shared__ int wtot[4];
  if (lane == 63) wtot[wave] = incl;
  __syncthreads();
  int wofs = 0;
  for (int wv = 0; wv < wave; ++wv) wofs += wtot[wv];
  int excl = wofs + incl - s;
#pragma unroll
  for (int i = 0; i < 8; ++i) pofs[base + i] = excl + c[i];
  if (t == 255) *nact = wofs + incl;
}

// ---- build tables: g1t[k][m] (full) and nidxtc[k][ci] (ordered-compacted) ---
__global__ void k_nidx(const int* __restrict__ coords, const int* __restrict__ grid,
                       const int* __restrict__ pidx, const int* __restrict__ mbits,
                       const int* __restrict__ pofs, int* __restrict__ g1t,
                       int* __restrict__ nidxtc) {
  int idx = blockIdx.x * 256 + threadIdx.x;
  if (idx >= M * 27) return;
  int m = idx & (M - 1);          // M = 2^14
  int k = idx >> 14;
  int p = m >> 3, j = m & 7;
  int dx = k / 9 - 1;
  int dy = (k / 3) % 3 - 1;
  int dz = k % 3 - 1;
  int x = coords[p * 3 + 0] * 2 + ((j >> 2) & 1) + 1 + dx;
  int y = coords[p * 3 + 1] * 2 + ((j >> 1) & 1) + 1 + dy;
  int z = coords[p * 3 + 2] * 2 + (j & 1) + 1 + dz;
  int gv = grid[(x * G + y) * G + z];
  g1t[idx] = (gv == M) ? N : pidx[gv];  // index into U (N = skip/zero)
  int mb = mbits[p];
  if ((mb >> j) & 1) {
    int ci = pofs[p] + __popc(mb & ((1 << j) - 1));  // order-preserving slot
    nidxtc[(size_t)k * M + ci] = gv;                 // index into h1
  }
}

// ---------------- skip GEMM: s = feats @ skip_w + skip_b  (f32) --------------
__global__ __launch_bounds__(256) void k_skip(const float* __restrict__ feats,
                                              const float* __restrict__ skw,
                                              const float* __restrict__ skb,
                                              float* __restrict__ s) {
  __shared__ float tile[32][36];
  int t = threadIdx.x;
  int rb = (blockIdx.x >> 1) * 32;        // 32 rows per block
  int ob = (blockIdx.x & 1) * 64;         // 64-col half
  int o = ob + (t & 63);
  int rg = (t >> 6) * 8;                  // 8 rows per wave-group
  float acc[8] = {0, 0, 0, 0, 0, 0, 0, 0};
  for (int cb = 0; cb < C; cb += 32) {
    __syncthreads();
    int row = t >> 3, cc = (t & 7) * 4;
    *(float4*)&tile[row][cc] =
        *(const float4*)(feats + (size_t)(rb + row) * C + cb + cc);
    __syncthreads();
    for (int c = 0; c < 32; ++c) {
      float wv = skw[(size_t)(cb + c) * CO + o];
#pragma unroll
      for (int r = 0; r < 8; ++r) acc[r] += tile[rg + r][c] * wv;
    }
  }
  float bv = skb[o];
#pragma unroll
  for (int r = 0; r < 8; ++r) s[(size_t)(rb + rg + r) * CO + o] = acc[r] + bv;
}

// ---------------- dense GEMM: U[n][k*128+o] = h[n][:] . w1t[k][o][:]  --------
// Output U stored as bf16 (halves write traffic vs f32).
template <int CIN, int NCB>
__global__ __launch_bounds__(256, 3) void k_dgemm(
    const unsigned short* __restrict__ src, const unsigned short* __restrict__ wt,
    unsigned short* __restrict__ U) {
  __shared__ unsigned short sA[2][128 * 32];
  __shared__ unsigned short sB[2][128 * 32];
  const int t = threadIdx.x;
  const int w = t >> 6, lane = t & 63;
  const int quad = lane >> 4, ln = lane & 15;
  const int m0 = blockIdx.x * 128;
  const int k = blockIdx.y;                  // tap index = 128-col block of U
  const int rh = (w >> 1) * 64, ch = (w & 1) * 64;

  const int row2 = t >> 1;
  const int c0 = (t & 1) * 2;
  const int x3 = (row2 >> 1) & 3;
  const int wsl0 = row2 * 32 + ((c0) ^ x3) * 8;
  const int wsl1 = row2 * 32 + ((c0 + 1) ^ x3) * 8;

  const unsigned short* pa_base = src + (size_t)(m0 + row2) * CIN + c0 * 8;
  const unsigned short* pb_base =
      wt + ((size_t)k * CO + row2) * CIN + c0 * 8;

  bf8 ra0, ra1, rb0, rb1;
  auto loadreg = [&](int s) {
    const unsigned short* pa = pa_base + s * 32;
    const unsigned short* pb = pb_base + s * 32;
    ra0 = *(const bf8*)(pa);
    ra1 = *(const bf8*)(pa + 8);
    rb0 = *(const bf8*)(pb);
    rb1 = *(const bf8*)(pb + 8);
  };
  auto writelds = [&](int buf) {
    *(bf8*)(sA[buf] + wsl0) = ra0;
    *(bf8*)(sA[buf] + wsl1) = ra1;
    *(bf8*)(sB[buf] + wsl0) = rb0;
    *(bf8*)(sB[buf] + wsl1) = rb1;
  };

  f4 acc[16];
  f4 zero = {0.f, 0.f, 0.f, 0.f};
#pragma unroll
  for (int i = 0; i < 16; ++i) acc[i] = zero;

  const int slot = (quad ^ ((ln >> 1) & 3)) * 8;

  loadreg(0);
  writelds(0);
  for (int s = 0; s < NCB; ++s) {
    const bool have = (s + 1 < NCB);
    if (have) loadreg(s + 1);
    __syncthreads();
    const unsigned short* pa = sA[s & 1];
    const unsigned short* pb = sB[s & 1];
    bf8 av[4], bv[4];
#pragma unroll
    for (int ti = 0; ti < 4; ++ti)
      av[ti] = *(const bf8*)(pa + (rh + ti * 16 + ln) * 32 + slot);
#pragma unroll
    for (int tj = 0; tj < 4; ++tj)
      bv[tj] = *(const bf8*)(pb + (ch + tj * 16 + ln) * 32 + slot);
#pragma unroll
    for (int ti = 0; ti < 4; ++ti)
#pragma unroll
      for (int tj = 0; tj < 4; ++tj)
        acc[ti * 4 + tj] = __builtin_amdgcn_mfma_f32_16x16x32_bf16(
            av[ti], bv[tj], acc[ti * 4 + tj], 0, 0, 0);
    if (have) writelds((s + 1) & 1);
  }

  // store bf16: D layout col=ln, row=quad*4+rr; U row stride UW=3456
#pragma unroll
  for (int ti = 0; ti < 4; ++ti) {
    int mrow = rh + ti * 16 + quad * 4;
#pragma unroll
    for (int tj = 0; tj < 4; ++tj) {
      int co = ch + tj * 16 + ln;
#pragma unroll
      for (int rr = 0; rr < 4; ++rr)
        U[(size_t)(m0 + mrow + rr) * UW + k * CO + co] =
            f2bf(acc[ti * 4 + tj][rr]);
    }
  }
}

// --- conv1 combine: out1[m] = sum_k U[g1t[k][m]][k*128+:] + b1; LN; silu -> h1
__global__ __launch_bounds__(256) void k_g1sum(
    const unsigned short* __restrict__ U, const int* __restrict__ g1t,
    const float* __restrict__ b1, unsigned short* __restrict__ h1) {
  int wave = threadIdx.x >> 6, lane = threadIdx.x & 63;
  int m = blockIdx.x * 4 + wave;
  float a0 = b1[2 * lane], a1 = b1[2 * lane + 1];
#pragma unroll
  for (int k = 0; k < 27; ++k) {
    int g = g1t[k * M + m];          // wave-uniform
    if (g < N) {
      ushort2 v = *(const ushort2*)(U + (size_t)g * UW + k * CO + 2 * lane);
      a0 += bf2f(v.x); a1 += bf2f(v.y);
    }
  }
  float sum = a0 + a1, sq = a0 * a0 + a1 * a1;
#pragma unroll
  for (int mk = 1; mk < 64; mk <<= 1) {
    sum += __shfl_xor(sum, mk, 64);
    sq  += __shfl_xor(sq, mk, 64);
  }
  float mean = sum / (float)CO;
  float var  = sq / (float)CO - mean * mean;
  float rstd = rsqrtf(var + EPS);
  float y0 = (a0 - mean) * rstd;
  float y1 = (a1 - mean) * rstd;
  float s0 = y0 / (1.f + __expf(-y0));
  float s1 = y1 / (1.f + __expf(-y1));
  *(ushort2*)(h1 + (size_t)m * CO + 2 * lane) = ushort2{f2bf(s0), f2bf(s1)};
}

// ---- implicit-GEMM conv2 over ORDERED-compacted active rows; early-exit -----
template <int CIN, int NCB, int KCH>
__global__ __launch_bounds__(256, 3) void k_conv(
    const unsigned short* __restrict__ src, const int* __restrict__ gt,
    const unsigned short* __restrict__ wt, unsigned short* __restrict__ part,
    const int* __restrict__ nact) {
  const int m0 = blockIdx.x * 128;
  if (m0 >= *nact) return;             // whole block past the active range
  __shared__ unsigned short sA[2][128 * 32];   // 8 KB per buf
  __shared__ unsigned short sB[2][128 * 32];
  const int t = threadIdx.x;
  const int w = t >> 6, lane = t & 63;
  const int quad = lane >> 4, ln = lane & 15;
  const int kpart = blockIdx.y;
  const int k0 = kpart * KCH;
  const int nk = min(KCH, 27 - k0);
  const int nstage = nk * NCB;
  const int rh = (w >> 1) * 64, ch = (w & 1) * 64;

  const int row2 = t >> 1;
  const int c0 = (t & 1) * 2;
  const int x3 = (row2 >> 1) & 3;
  const int wsl0 = row2 * 32 + ((c0) ^ x3) * 8;
  const int wsl1 = row2 * 32 + ((c0 + 1) ^ x3) * 8;

  int ga[KCH];
#pragma unroll
  for (int kk = 0; kk < KCH; ++kk)
    ga[kk] = (kk < nk) ? gt[(size_t)(k0 + kk) * M + m0 + row2] : 0;

  bf8 ra0, ra1, rb0, rb1;
  auto loadreg = [&](int s) {
    const int kk = s / NCB;
    const int cb = s - kk * NCB;
    const unsigned short* pa = src + (size_t)ga[kk] * CIN + cb * 32 + c0 * 8;
    const unsigned short* pb =
        wt + ((size_t)(k0 + kk) * CO + row2) * CIN + cb * 32 + c0 * 8;
    ra0 = *(const bf8*)(pa);
    ra1 = *(const bf8*)(pa + 8);
    rb0 = *(const bf8*)(pb);
    rb1 = *(const bf8*)(pb + 8);
  };
  auto writelds = [&](int buf) {
    *(bf8*)(sA[buf] + wsl0) = ra0;
    *(bf8*)(sA[buf] + wsl1) = ra1;
    *(bf8*)(sB[buf] + wsl0) = rb0;
    *(bf8*)(sB[buf] + wsl1) = rb1;
  };

  f4 acc[16];
  f4 zero = {0.f, 0.f, 0.f, 0.f};
#pragma unroll
  for (int i = 0; i < 16; ++i) acc[i] = zero;

  const int slot = (quad ^ ((ln >> 1) & 3)) * 8;

  loadreg(0);
  writelds(0);
  for (int s = 0; s < nstage; ++s) {
    const bool have = (s + 1 < nstage);
    if (have) loadreg(s + 1);
    __syncthreads();
    const unsigned short* pa = sA[s & 1];
    const unsigned short* pb = sB[s & 1];
    bf8 av[4], bv[4];
#pragma unroll
    for (int ti = 0; ti < 4; ++ti)
      av[ti] = *(const bf8*)(pa + (rh + ti * 16 + ln) * 32 + slot);
#pragma unroll
    for (int tj = 0; tj < 4; ++tj)
      bv[tj] = *(const bf8*)(pb + (ch + tj * 16 + ln) * 32 + slot);
#pragma unroll
    for (int ti = 0; ti < 4; ++ti)
#pragma unroll
      for (int tj = 0; tj < 4; ++tj)
        acc[ti * 4 + tj] = __builtin_amdgcn_mfma_f32_16x16x32_bf16(
            av[ti], bv[tj], acc[ti * 4 + tj], 0, 0, 0);
    if (have) writelds((s + 1) & 1);
  }

  unsigned short* pp = part + ((size_t)kpart * M + m0) * CO;
#pragma unroll
  for (int ti = 0; ti < 4; ++ti) {
    int mrow = rh + ti * 16 + quad * 4;
#pragma unroll
    for (int tj = 0; tj < 4; ++tj) {
      int co = ch + tj * 16 + ln;
#pragma unroll
      for (int rr = 0; rr < 4; ++rr)
        pp[(size_t)(mrow + rr) * CO + co] = f2bf(acc[ti * 4 + tj][rr]);
    }
  }
}

// -- reduce 2: inactive m -> zeros; active -> sum partials[ci] + bias + skip --
__global__ __launch_bounds__(256) void k_r2(const unsigned short* __restrict__ p,
                                            const float* __restrict__ bias,
                                            const float* __restrict__ sres,
                                            const int* __restrict__ mbits,
                                            const int* __restrict__ pofs,
                                            float* __restrict__ out) {
  int i = blockIdx.x * 256 + threadIdx.x;   // i in [0, M*CO/4)
  int m = i >> 5;                            // 32 groups of 4 per row
  int o4 = (i & 31) * 4;
  int pr = m >> 3, j = m & 7;
  int mb = mbits[pr];
  float4 r = {0.f, 0.f, 0.f, 0.f};
  if ((mb >> j) & 1) {
    int ci = pofs[pr] + __popc(mb & ((1 << j) - 1));
    float4 acc = *(const float4*)(bias + o4);
#pragma unroll
    for (int q = 0; q < KP2; ++q) {
      ushort4 a = *(const ushort4*)(p + ((size_t)q * M + ci) * CO + o4);
      acc.x += bf2f(a.x); acc.y += bf2f(a.y);
      acc.z += bf2f(a.z); acc.w += bf2f(a.w);
    }
    float4 s = *(const float4*)(sres + (size_t)pr * CO + o4);
    r.x = acc.x + s.x;
    r.y = acc.y + s.y;
    r.z = acc.z + s.z;
    r.w = acc.w + s.w;
  }
  *(float4*)(out + (size_t)m * CO + o4) = r;
}

// ---------------- launcher ----------------------------------------------------
extern "C" void kernel_launch(void* const* d_in, const int* in_sizes, int n_in,
                              void* d_out, int out_size, void* d_ws, size_t ws_size,
                              hipStream_t stream) {
  const float* feats = (const float*)d_in[0];
  const float* n1w   = (const float*)d_in[1];
  const float* n1b   = (const float*)d_in[2];
  const float* sdw   = (const float*)d_in[3];
  const float* sdb   = (const float*)d_in[4];
  const float* c1w   = (const float*)d_in[5];
  const float* c1b   = (const float*)d_in[6];
  const float* c2w   = (const float*)d_in[7];
  const float* c2b   = (const float*)d_in[8];
  const float* skw   = (const float*)d_in[9];
  const float* skb   = (const float*)d_in[10];
  const int* coords  = (const int*)d_in[11];
  float* out = (float*)d_out;   // [M*CO] conv output, then [N*8] subdiv

  char* ws = (char*)d_ws;
  size_t off = 0;
  auto alloc = [&](size_t bytes) -> char* {
    char* p = ws + off;
    off += (bytes + 255) & ~(size_t)255;
    return p;
  };
  unsigned short* h    = (unsigned short*)alloc((size_t)(N + 1) * C * 2);
  unsigned short* h1   = (unsigned short*)alloc((size_t)(M + 1) * CO * 2);
  int*   grid   = (int*)alloc((size_t)G * G * G * 4);
  int*   nidxtc = (int*)alloc((size_t)27 * M * 4);
  int*   g1t    = (int*)alloc((size_t)27 * M * 4);
  int*   pidx   = (int*)alloc((size_t)M * 4);
  int*   mbits  = (int*)alloc((size_t)N * 4);
  int*   pofs   = (int*)alloc((size_t)N * 4);
  int*   nact   = (int*)alloc(256);
  float* sres   = (float*)alloc((size_t)N * CO * 4);
  unsigned short* w1t = (unsigned short*)alloc((size_t)27 * CO * C * 2);
  unsigned short* w2t = (unsigned short*)alloc((size_t)27 * CO * CO * 2);
  unsigned short* U = (unsigned short*)alloc((size_t)N * UW * 2);   // 14.2 MB bf16
  unsigned short* pc  = (unsigned short*)alloc((size_t)KP2 * M * CO * 2);

  k_prep<<<(27 * C * CO + 255) / 256, 256, 0, stream>>>(grid, h, h1, c1w, w1t,
                                                        c2w, w2t, nidxtc);
  k_rownorm<<<N, 256, 0, stream>>>(feats, n1w, n1b, sdw, sdb,
                                   out + (size_t)M * CO, h, pidx, mbits,
                                   coords, grid);
  k_scan<<<1, 256, 0, stream>>>(mbits, pofs, nact);
  k_nidx<<<(M * 27 + 255) / 256, 256, 0, stream>>>(coords, grid, pidx, mbits,
                                                   pofs, g1t, nidxtc);
  k_skip<<<128, 256, 0, stream>>>(feats, skw, skb, sres);

  // conv1 via factorization: dense U-GEMM (2048 x 3456 x 256), bf16 output ...
  k_dgemm<C, 8><<<dim3(N / 128, 27), 256, 0, stream>>>(h, w1t, U);
  // ... then gather-add over 27 taps, fused bias + LN + silu -> h1
  k_g1sum<<<M / 4, 256, 0, stream>>>(U, g1t, c1b, h1);

  // conv2: implicit GEMM over ordered-compacted active rows (~M/2), k-split 4x7
  k_conv<CO, 4, KCHUNK2><<<dim3(M / 128, KP2), 256, 0, stream>>>(h1, nidxtc,
                                                                 w2t, pc, nact);
  k_r2<<<M * CO / 4 / 256, 256, 0, stream>>>(pc, c2b, sres, mbits, pofs, out);
}